// Round 1
// baseline (135.178 us; speedup 1.0000x reference)
//
#include <hip/hip_runtime.h>

#define NB 32
#define N0 20000
#define N1 10000
#define N2 10000
#define NP 40000           // N0+N1+N2
#define NK 64
#define TILES 625          // NP / 64
#define CHUNKS 16          // blocks per (b, side)
#define STRIDE (CHUNKS*4)  // waves per (b, side)

__global__ __launch_bounds__(256) void hat_kernel(
    const float* __restrict__ up0, const float* __restrict__ down0,
    const float* __restrict__ ext0, const float* __restrict__ ext1,
    const float* __restrict__ centers, const float* __restrict__ radius,
    float* __restrict__ out)
{
    const int lane = threadIdx.x & 63;
    const int wave = threadIdx.x >> 6;
    const int chunk = blockIdx.x;
    const int b    = blockIdx.y;
    const int side = blockIdx.z;   // 0 = up, 1 = down

    // lane k owns center k (K == wave size)
    const float cx = centers[2*lane];
    const float cy = centers[2*lane+1];
    const float r  = fabsf(radius[0]);

    const float* base0 = (side == 0 ? up0 : down0) + (size_t)b * (N0*2);
    const float* e0    = ext0 + (size_t)b * (N1*2);
    const float* e1    = ext1 + (size_t)b * (N2*2);
    const int sel = (side == 0) ? 1 : 0;   // up uses y, down uses x

    float acc = 0.f;

    for (int t = chunk*4 + wave; t < TILES; t += STRIDE) {
        const int p = t*64 + lane;
        float px, py;
        if (p < N0) {
            px = base0[2*p];
            py = base0[2*p+1];
        } else if (p < N0 + N1) {
            const int i = p - N0;
            const float v = e0[2*i + sel];
            px = v; py = 1.0f - v;
        } else {
            const int i = p - (N0 + N1);
            const float v = e1[2*i + sel];
            px = v; py = 1.0f - v;
        }

        #pragma unroll
        for (int j = 0; j < 64; ++j) {
            const float qx = __shfl(px, j, 64);
            const float qy = __shfl(py, j, 64);
            // n = L1 distance; abs folds into VOP3 input modifiers
            const float n  = fabsf(qx - cx) + fabsf(qy - cy);
            // 1/(1+n) - 1/(1+|r-n|) == (|r-n| - n) / ((1+n)*(1+|r-n|))
            const float rn = r - n;
            const float a  = 1.0f + n;
            const float bb = 1.0f + fabsf(rn);
            const float rc = __builtin_amdgcn_rcpf(a * bb);
            acc = fmaf(fabsf(rn) - n, rc, acc);
        }
    }

    __shared__ float red[4][64];
    red[wave][lane] = acc;
    __syncthreads();
    if (wave == 0) {
        const float s = red[0][lane] + red[1][lane] + red[2][lane] + red[3][lane];
        atomicAdd(&out[b*128 + side*64 + lane], s);
    }
}

__global__ __launch_bounds__(256) void tpl_kernel(float* __restrict__ out)
{
    __shared__ float red[256];
    float s = 0.f;
    for (int i = threadIdx.x; i < NB*NK; i += 256) {
        const int b = i >> 6, k = i & 63;
        const float d = out[b*128 + k] - out[b*128 + 64 + k];
        s = fmaf(d, d, s);
    }
    red[threadIdx.x] = s;
    __syncthreads();
    for (int w = 128; w > 0; w >>= 1) {
        if (threadIdx.x < w) red[threadIdx.x] += red[threadIdx.x + w];
        __syncthreads();
    }
    if (threadIdx.x == 0) out[NB*2*NK] = -red[0];
}

extern "C" void kernel_launch(void* const* d_in, const int* in_sizes, int n_in,
                              void* d_out, int out_size, void* d_ws, size_t ws_size,
                              hipStream_t stream) {
    const float* up0     = (const float*)d_in[0];
    const float* down0   = (const float*)d_in[1];
    const float* ext0    = (const float*)d_in[2];
    const float* ext1    = (const float*)d_in[3];
    const float* centers = (const float*)d_in[4];
    const float* radius  = (const float*)d_in[5];
    float* out = (float*)d_out;

    // accumulator region must start at zero (harness poisons d_out with 0xAA)
    hipMemsetAsync(out, 0, NB * 2 * NK * sizeof(float), stream);

    dim3 grid(CHUNKS, NB, 2);
    hat_kernel<<<grid, 256, 0, stream>>>(up0, down0, ext0, ext1, centers, radius, out);
    tpl_kernel<<<1, 256, 0, stream>>>(out);
}

// Round 2
// 126.246 us; speedup vs baseline: 1.0708x; 1.0708x over previous
//
#include <hip/hip_runtime.h>

#define NB 32
#define N0 20000
#define N1 10000
#define N2 10000
#define NP 40000           // N0+N1+N2
#define NK 64
#define TILES 625          // NP / 64
#define CHUNKS 8           // blocks along tile dim per (b, side, cchunk)
#define KC 16              // centers per chunk (4 chunks of 16)

__global__ __launch_bounds__(256) void hat_kernel(
    const float* __restrict__ up0, const float* __restrict__ down0,
    const float* __restrict__ ext0, const float* __restrict__ ext1,
    const float* __restrict__ centers, const float* __restrict__ radius,
    float* __restrict__ out)
{
    const int lane  = threadIdx.x & 63;
    const int wave  = threadIdx.x >> 6;
    const int b     = blockIdx.y;
    const int side  = blockIdx.z >> 2;    // 0 = up, 1 = down
    const int cc    = blockIdx.z & 3;     // center chunk
    const int cbase = cc * KC;

    // centers for this chunk: wave-uniform addresses -> s_load, live in SGPRs
    float cx[KC], cy[KC];
    #pragma unroll
    for (int k = 0; k < KC; ++k) {
        cx[k] = centers[2*(cbase+k)];
        cy[k] = centers[2*(cbase+k)+1];
    }
    const float r  = fabsf(radius[0]);
    const float r1 = 1.0f + r;

    const float2* base0 = (const float2*)((side == 0 ? up0 : down0) + (size_t)b * (N0*2));
    const float2* e0    = (const float2*)(ext0 + (size_t)b * (N1*2));
    const float2* e1    = (const float2*)(ext1 + (size_t)b * (N2*2));

    float acc[KC];
    #pragma unroll
    for (int k = 0; k < KC; ++k) acc[k] = 0.f;

    for (int t = blockIdx.x*4 + wave; t < TILES; t += CHUNKS*4) {
        const int p = t*64 + lane;   // this lane's point
        float px, py;
        if (p < N0) {
            float2 v = base0[p];
            px = v.x; py = v.y;
        } else if (p < N0 + N1) {
            float2 v = e0[p - N0];
            float vv = (side == 0) ? v.y : v.x;   // up uses y, down uses x
            px = vv; py = 1.0f - vv;
        } else {
            float2 v = e1[p - (N0 + N1)];
            float vv = (side == 0) ? v.y : v.x;
            px = vv; py = 1.0f - vv;
        }

        #pragma unroll
        for (int k = 0; k < KC; ++k) {
            const float t1 = px - cx[k];
            const float t2 = py - cy[k];
            const float n  = fabsf(t1) + fabsf(t2);
            const float u  = 1.0f + n;            // 1 + n
            const float rn = r1 - u;              // r - n
            const float bb = 1.0f + fabsf(rn);    // 1 + |r-n|
            const float rc = __builtin_amdgcn_rcpf(u * bb);
            acc[k] = fmaf(bb - u, rc, acc[k]);    // (|r-n| - n) / ((1+n)(1+|r-n|))
        }
    }

    // multi-accumulator butterfly: lane group ends with per-center totals.
    // After steps m=32,16,8,4 (array halving), acc[0] at lane l holds center
    // (l>>2)&15 summed over the 16 lanes sharing (l&3); two more xor steps
    // finish the sum over all 64 lanes.
    {
        #pragma unroll
        for (int k = 0; k < 8; ++k) {
            const bool hi = lane & 32;
            const float send = hi ? acc[k]   : acc[k+8];
            const float keep = hi ? acc[k+8] : acc[k];
            acc[k] = keep + __shfl_xor(send, 32, 64);
        }
        #pragma unroll
        for (int k = 0; k < 4; ++k) {
            const bool hi = lane & 16;
            const float send = hi ? acc[k]   : acc[k+4];
            const float keep = hi ? acc[k+4] : acc[k];
            acc[k] = keep + __shfl_xor(send, 16, 64);
        }
        #pragma unroll
        for (int k = 0; k < 2; ++k) {
            const bool hi = lane & 8;
            const float send = hi ? acc[k]   : acc[k+2];
            const float keep = hi ? acc[k+2] : acc[k];
            acc[k] = keep + __shfl_xor(send, 8, 64);
        }
        {
            const bool hi = lane & 4;
            const float send = hi ? acc[0] : acc[1];
            const float keep = hi ? acc[1] : acc[0];
            acc[0] = keep + __shfl_xor(send, 4, 64);
        }
        acc[0] += __shfl_xor(acc[0], 2, 64);
        acc[0] += __shfl_xor(acc[0], 1, 64);
    }
    if ((lane & 3) == 0) {
        atomicAdd(&out[b*128 + side*64 + cbase + (lane >> 2)], acc[0]);
    }
}

__global__ __launch_bounds__(256) void tpl_kernel(float* __restrict__ out)
{
    __shared__ float red[256];
    float s = 0.f;
    for (int i = threadIdx.x; i < NB*NK; i += 256) {
        const int b = i >> 6, k = i & 63;
        const float d = out[b*128 + k] - out[b*128 + 64 + k];
        s = fmaf(d, d, s);
    }
    red[threadIdx.x] = s;
    __syncthreads();
    for (int w = 128; w > 0; w >>= 1) {
        if (threadIdx.x < w) red[threadIdx.x] += red[threadIdx.x + w];
        __syncthreads();
    }
    if (threadIdx.x == 0) out[NB*2*NK] = -red[0];
}

extern "C" void kernel_launch(void* const* d_in, const int* in_sizes, int n_in,
                              void* d_out, int out_size, void* d_ws, size_t ws_size,
                              hipStream_t stream) {
    const float* up0     = (const float*)d_in[0];
    const float* down0   = (const float*)d_in[1];
    const float* ext0    = (const float*)d_in[2];
    const float* ext1    = (const float*)d_in[3];
    const float* centers = (const float*)d_in[4];
    const float* radius  = (const float*)d_in[5];
    float* out = (float*)d_out;

    // accumulator region must start at zero (harness poisons d_out with 0xAA)
    hipMemsetAsync(out, 0, NB * 2 * NK * sizeof(float), stream);

    dim3 grid(CHUNKS, NB, 8);   // z = side*4 + center-chunk
    hat_kernel<<<grid, 256, 0, stream>>>(up0, down0, ext0, ext1, centers, radius, out);
    tpl_kernel<<<1, 256, 0, stream>>>(out);
}

// Round 3
// 121.139 us; speedup vs baseline: 1.1159x; 1.0422x over previous
//
#include <hip/hip_runtime.h>

#define NB 32
#define N0 20000
#define N1 10000
#define N2 10000
#define NP 40000           // N0+N1+N2
#define NK 64
#define TILES 625          // NP / 64
#define CHUNKS 8           // blocks along tile dim per (b, side, cchunk)
#define KC 16              // centers per chunk (4 chunks of 16)

#define TBL_N 256          // table entries
#define TBL_R 8            // replicas (8 lanes share one replica)
#define TBL_H (1.0f/120.0f)      // cell width in n
#define TBL_SCALE (120.0f*64.0f) // n -> byte-scaled t  (64 B per entry-row step / 8 B elem * 8 reps)

__global__ __launch_bounds__(256) void hat_kernel(
    const float* __restrict__ up0, const float* __restrict__ down0,
    const float* __restrict__ ext0, const float* __restrict__ ext1,
    const float* __restrict__ centers, const float* __restrict__ radius,
    float* __restrict__ out)
{
    const int lane  = threadIdx.x & 63;
    const int wave  = threadIdx.x >> 6;
    const int b     = blockIdx.y;
    const int side  = blockIdx.z >> 2;    // 0 = up, 1 = down
    const int cc    = blockIdx.z & 3;     // center chunk
    const int cbase = cc * KC;

    // ---- build piecewise-linear table for g(n) = 1/(1+n) - 1/(1+|r-n|) ----
    // layout: tab[i*TBL_R + c], replica c serves lanes [8c..8c+7].
    // byte addr = i*64 + c*8  ->  word banks {2c,2c+1} rotate with i parity;
    // a wave-read is always the minimum 4 word-accesses/bank.
    __shared__ float2 tab[TBL_N * TBL_R];   // 16 KB
    const float r = fabsf(radius[0]);
    {
        const int e = threadIdx.x;          // 256 threads, 256 entries
        const float n0 = e * TBL_H, n1 = (e + 1) * TBL_H;
        const float g0 = 1.0f/(1.0f+n0) - 1.0f/(1.0f + fabsf(r - n0));
        const float g1 = 1.0f/(1.0f+n1) - 1.0f/(1.0f + fabsf(r - n1));
        const float dT = g1 - g0;
        float2 v;
        v.x = g0 - (float)e * dT;           // A[i]
        v.y = dT * (1.0f/64.0f);            // B[i], pre-divided for byte-scaled t
        #pragma unroll
        for (int c = 0; c < TBL_R; ++c) tab[e*TBL_R + c] = v;
    }
    __syncthreads();

    // centers for this chunk: wave-uniform -> SGPRs
    float cx[KC], cy[KC];
    #pragma unroll
    for (int k = 0; k < KC; ++k) {
        cx[k] = centers[2*(cbase+k)];
        cy[k] = centers[2*(cbase+k)+1];
    }

    const float2* base0 = (const float2*)((side == 0 ? up0 : down0) + (size_t)b * (N0*2));
    const float2* e0    = (const float2*)(ext0 + (size_t)b * (N1*2));
    const float2* e1    = (const float2*)(ext1 + (size_t)b * (N2*2));

    const unsigned laneoff = (unsigned)(lane & 56);   // (lane>>3)*8 bytes
    const char* tbase = (const char*)tab;

    float acc[KC];
    #pragma unroll
    for (int k = 0; k < KC; ++k) acc[k] = 0.f;

    for (int t = blockIdx.x*4 + wave; t < TILES; t += CHUNKS*4) {
        const int p = t*64 + lane;   // this lane's point
        float px, py;
        if (p < N0) {
            float2 v = base0[p];
            px = v.x; py = v.y;
        } else if (p < N0 + N1) {
            float2 v = e0[p - N0];
            float vv = (side == 0) ? v.y : v.x;   // up uses y, down uses x
            px = vv; py = 1.0f - vv;
        } else {
            float2 v = e1[p - (N0 + N1)];
            float vv = (side == 0) ? v.y : v.x;
            px = vv; py = 1.0f - vv;
        }

        #pragma unroll
        for (int k = 0; k < KC; ++k) {
            const float dx = px - cx[k];
            const float dy = py - cy[k];
            const float tt = fmaf(fabsf(dx), TBL_SCALE, fabsf(dy) * TBL_SCALE);
            const unsigned iv  = (unsigned)tt;               // trunc
            const unsigned off = (iv & 0xFFFFFFC0u) | laneoff;
            const float2 ab = *(const float2*)(tbase + off); // ds_read_b64
            acc[k] += fmaf(tt, ab.y, ab.x);
        }
    }

    // multi-accumulator butterfly: ends with center (lane>>2)&15 in acc[0]
    {
        #pragma unroll
        for (int k = 0; k < 8; ++k) {
            const bool hi = lane & 32;
            const float send = hi ? acc[k]   : acc[k+8];
            const float keep = hi ? acc[k+8] : acc[k];
            acc[k] = keep + __shfl_xor(send, 32, 64);
        }
        #pragma unroll
        for (int k = 0; k < 4; ++k) {
            const bool hi = lane & 16;
            const float send = hi ? acc[k]   : acc[k+4];
            const float keep = hi ? acc[k+4] : acc[k];
            acc[k] = keep + __shfl_xor(send, 16, 64);
        }
        #pragma unroll
        for (int k = 0; k < 2; ++k) {
            const bool hi = lane & 8;
            const float send = hi ? acc[k]   : acc[k+2];
            const float keep = hi ? acc[k+2] : acc[k];
            acc[k] = keep + __shfl_xor(send, 8, 64);
        }
        {
            const bool hi = lane & 4;
            const float send = hi ? acc[0] : acc[1];
            const float keep = hi ? acc[1] : acc[0];
            acc[0] = keep + __shfl_xor(send, 4, 64);
        }
        acc[0] += __shfl_xor(acc[0], 2, 64);
        acc[0] += __shfl_xor(acc[0], 1, 64);
    }
    if ((lane & 3) == 0) {
        atomicAdd(&out[b*128 + side*64 + cbase + (lane >> 2)], acc[0]);
    }
}

__global__ __launch_bounds__(256) void tpl_kernel(float* __restrict__ out)
{
    __shared__ float red[256];
    float s = 0.f;
    for (int i = threadIdx.x; i < NB*NK; i += 256) {
        const int b = i >> 6, k = i & 63;
        const float d = out[b*128 + k] - out[b*128 + 64 + k];
        s = fmaf(d, d, s);
    }
    red[threadIdx.x] = s;
    __syncthreads();
    for (int w = 128; w > 0; w >>= 1) {
        if (threadIdx.x < w) red[threadIdx.x] += red[threadIdx.x + w];
        __syncthreads();
    }
    if (threadIdx.x == 0) out[NB*2*NK] = -red[0];
}

extern "C" void kernel_launch(void* const* d_in, const int* in_sizes, int n_in,
                              void* d_out, int out_size, void* d_ws, size_t ws_size,
                              hipStream_t stream) {
    const float* up0     = (const float*)d_in[0];
    const float* down0   = (const float*)d_in[1];
    const float* ext0    = (const float*)d_in[2];
    const float* ext1    = (const float*)d_in[3];
    const float* centers = (const float*)d_in[4];
    const float* radius  = (const float*)d_in[5];
    float* out = (float*)d_out;

    // accumulator region must start at zero (harness poisons d_out with 0xAA)
    hipMemsetAsync(out, 0, NB * 2 * NK * sizeof(float), stream);

    dim3 grid(CHUNKS, NB, 8);   // z = side*4 + center-chunk
    hat_kernel<<<grid, 256, 0, stream>>>(up0, down0, ext0, ext1, centers, radius, out);
    tpl_kernel<<<1, 256, 0, stream>>>(out);
}